// Round 10
// baseline (692.561 us; speedup 1.0000x reference)
//
#include <hip/hip_runtime.h>
#include <hip/hip_fp16.h>
#include <math.h>

#define NNODES 262144   // total nodes
#define NNPG   1024     // nodes per graph
#define NGRAPH 256      // graphs
#define INCH   32       // in channels
#define HD     128      // hidden
#define MAXN   8
#define NEDGE  2097152

using half8  = __attribute__((ext_vector_type(8))) _Float16;
using floatx4 = __attribute__((ext_vector_type(4))) float;

__device__ __forceinline__ float selu_f(float v){
    const float alpha = 1.6732632423543772f;
    const float scale = 1.0507009873554805f;
    return v > 0.f ? scale * v : scale * alpha * expm1f(v);
}

// ---------------- degree: 2-way shadow histogram (halves per-line RMW contention) ----
__global__ void k_deg(const int* __restrict__ dst, int* __restrict__ degA,
                      int* __restrict__ degB, int* __restrict__ ecur){
    int e = blockIdx.x * blockDim.x + threadIdx.x;
    int d = dst[e];
    int copy = e & 1;
    int* cp = copy ? degB : degA;
    int r = atomicAdd(&cp[d], 1);
    ecur[e] = (r << 1) | copy;
}

// merge totals: degB <- degA+degB (scanned later), dinv = rsqrt(total+1)
__global__ void k_dinv2(const int* __restrict__ degA, int* __restrict__ degB,
                        float* __restrict__ dinv){
    int i = blockIdx.x * blockDim.x + threadIdx.x;
    if (i < NNODES){
        int t = degA[i] + degB[i];
        degB[i] = t;
        dinv[i] = rsqrtf((float)t + 1.0f);
    }
}

// ---------------- prefix sum (3-pass) ----------------
__global__ __launch_bounds__(256) void k_scan1(const int* __restrict__ deg,
        int* __restrict__ indptr, int* __restrict__ bsum){
    int bid = blockIdx.x, tid = threadIdx.x;
    int4 v = ((const int4*)deg)[bid * 256 + tid];
    int s = v.x + v.y + v.z + v.w;
    int lane = tid & 63;
    int p = s;
    #pragma unroll
    for (int off = 1; off < 64; off <<= 1){
        int u = __shfl_up(p, off);
        if (lane >= off) p += u;
    }
    __shared__ int ws[4];
    if (lane == 63) ws[tid >> 6] = p;
    __syncthreads();
    int w = tid >> 6, wo = 0;
    if (w > 0) wo = ws[0];
    if (w > 1) wo += ws[1];
    if (w > 2) wo += ws[2];
    int excl = wo + p - s;
    int base = bid * 1024 + tid * 4;
    indptr[base + 0] = excl;
    indptr[base + 1] = excl + v.x;
    indptr[base + 2] = excl + v.x + v.y;
    indptr[base + 3] = excl + v.x + v.y + v.z;
    if (tid == 255) bsum[bid] = excl + s;
}

__global__ __launch_bounds__(256) void k_scan2(int* __restrict__ bsum){
    int tid = threadIdx.x;
    int v = bsum[tid];
    int lane = tid & 63;
    int p = v;
    #pragma unroll
    for (int off = 1; off < 64; off <<= 1){
        int u = __shfl_up(p, off);
        if (lane >= off) p += u;
    }
    __shared__ int ws[4];
    if (lane == 63) ws[tid >> 6] = p;
    __syncthreads();
    int w = tid >> 6, wo = 0;
    if (w > 0) wo = ws[0];
    if (w > 1) wo += ws[1];
    if (w > 2) wo += ws[2];
    bsum[tid] = wo + p - v;
}

__global__ __launch_bounds__(256) void k_scan3(int* __restrict__ indptr,
        const int* __restrict__ bsum){
    int bid = blockIdx.x;
    int off = bsum[bid];
    int4* p = (int4*)indptr + bid * 256 + threadIdx.x;
    int4 v = *p;
    v.x += off; v.y += off; v.z += off; v.w += off;
    *p = v;
    if (bid == 0 && threadIdx.x == 0) indptr[NNODES] = NEDGE;
}

// ---------------- fill CSR: atomic-free; copy-1 edges offset by degA[d] ----------------
__global__ void k_fill(const int* __restrict__ src, const int* __restrict__ dst,
        const int* __restrict__ indptr, const int* __restrict__ ecur,
        const int* __restrict__ degA, int* __restrict__ esrc){
    int e = blockIdx.x * blockDim.x + threadIdx.x;
    int d = dst[e];
    int ec = ecur[e];
    int pos = indptr[d] + (ec >> 1) + ((ec & 1) ? degA[d] : 0);
    esrc[pos] = src[e];
}

// ---------------- W prep: W f32 [KD][128] -> Wt f16 [128][KD] ----------------
__global__ void k_wprep(const float* __restrict__ W, __half* __restrict__ Wt, int KD){
    int idx = blockIdx.x * 256 + threadIdx.x;
    int c = idx / KD, k = idx - c * KD;
    Wt[idx] = __float2half(W[k * 128 + c]);
}

// ---------------- shared MFMA core: split-A [64 rows,128] @ Wt[128][128] -> acc ----
__device__ __forceinline__ void mfma128_stage(const __half* __restrict__ Alo,
        const __half* __restrict__ Ahi, const __half* __restrict__ Wt,
        __half* Xsm, __half* Wsm, int r0, int tid){
    #pragma unroll
    for (int it = 0; it < 2; ++it){
        int idx = tid + it * 256;       // 512 = 64 rows x 8 uint4
        int row = idx >> 3, q = idx & 7;
        *(uint4*)(Xsm + row * 136 + q * 8)      = *(const uint4*)(Alo + (size_t)(r0 + row) * 64 + q * 8);
        *(uint4*)(Xsm + row * 136 + 64 + q * 8) = *(const uint4*)(Ahi + (size_t)(r0 + row) * 128 + q * 8);
    }
    #pragma unroll
    for (int it = 0; it < 8; ++it){
        int idx = tid + it * 256;       // 2048 = 128 rows x 16 uint4
        int row = idx >> 4, q = idx & 15;
        *(uint4*)(Wsm + row * 136 + q * 8) = *(const uint4*)(Wt + (size_t)row * 128 + q * 8);
    }
}

__device__ __forceinline__ void mfma128_compute(const __half* Xsm, const __half* Wsm,
        int tid, floatx4 (&acc)[2][4]){
    const int wv = tid >> 6, lane = tid & 63, lr = lane & 15, lh = lane >> 4;
    const int rw = (wv >> 1) * 32;
    const int cw = (wv & 1) * 64;
    #pragma unroll
    for (int t = 0; t < 2; ++t)
        #pragma unroll
        for (int ct = 0; ct < 4; ++ct) acc[t][ct] = (floatx4){0.f, 0.f, 0.f, 0.f};
    #pragma unroll
    for (int s = 0; s < 4; ++s){
        int kb = s * 32 + lh * 8;
        half8 a0 = *(const half8*)(Xsm + (rw + lr) * 136 + kb);
        half8 a1 = *(const half8*)(Xsm + (rw + 16 + lr) * 136 + kb);
        #pragma unroll
        for (int ct = 0; ct < 4; ++ct){
            half8 b = *(const half8*)(Wsm + (cw + ct * 16 + lr) * 136 + kb);
            acc[0][ct] = __builtin_amdgcn_mfma_f32_16x16x32_f16(a0, b, acc[0][ct], 0, 0, 0);
            acc[1][ct] = __builtin_amdgcn_mfma_f32_16x16x32_f16(a1, b, acc[1][ct], 0, 0, 0);
        }
    }
}

// ---------------- layer-2 GEMM (split-A, dinv-scaled, to global) ----------------
__global__ __launch_bounds__(256) void k_mfma_sp(const __half* __restrict__ Alo,
        const __half* __restrict__ Ahi, const __half* __restrict__ Wt,
        const float* __restrict__ dinv, __half* __restrict__ Y){
    __shared__ __half Xsm[64 * 136];
    __shared__ __half Wsm[128 * 136];
    __shared__ float dvs[64];
    const int r0 = blockIdx.x * 64;
    const int tid = threadIdx.x;
    mfma128_stage(Alo, Ahi, Wt, Xsm, Wsm, r0, tid);
    if (tid < 64) dvs[tid] = dinv[r0 + tid];
    __syncthreads();
    floatx4 acc[2][4];
    mfma128_compute(Xsm, Wsm, tid, acc);
    const int wv = tid >> 6, lane = tid & 63, lr = lane & 15, lh = lane >> 4;
    const int rw = (wv >> 1) * 32, cw = (wv & 1) * 64;
    #pragma unroll
    for (int ct = 0; ct < 4; ++ct){
        int col = cw + ct * 16 + lr;
        #pragma unroll
        for (int t = 0; t < 2; ++t)
            #pragma unroll
            for (int reg = 0; reg < 4; ++reg){
                int rl = rw + t * 16 + lh * 4 + reg;
                Y[(size_t)(r0 + rl) * 128 + col] = __float2half(acc[t][ct][reg] * dvs[rl]);
            }
    }
}

// ---------------- fused K-GEMM + scores: st[b][k][i] = K_row . Q[b][i] ----------------
__global__ __launch_bounds__(256) void k_kscores(const __half* __restrict__ Alo,
        const __half* __restrict__ Ahi, const __half* __restrict__ Wt,
        const float* __restrict__ bias, const float* __restrict__ Qb,
        float* __restrict__ st){
    __shared__ __half Xsm[64 * 136];
    __shared__ __half Wsm[128 * 136];
    __shared__ __half Kbuf[64 * 136];
    __shared__ float Qs[8][132];
    const int r0 = blockIdx.x * 64;
    const int b  = r0 >> 10;
    const int tid = threadIdx.x;
    mfma128_stage(Alo, Ahi, Wt, Xsm, Wsm, r0, tid);
    #pragma unroll
    for (int it = 0; it < 4; ++it){
        int idx = tid + it * 256;       // 1024
        Qs[idx >> 7][idx & 127] = Qb[(size_t)(b * 8 + (idx >> 7)) * 128 + (idx & 127)];
    }
    __syncthreads();
    floatx4 acc[2][4];
    mfma128_compute(Xsm, Wsm, tid, acc);
    const int wv = tid >> 6, lane = tid & 63, lr = lane & 15, lh = lane >> 4;
    const int rw = (wv >> 1) * 32, cw = (wv & 1) * 64;
    #pragma unroll
    for (int ct = 0; ct < 4; ++ct){
        int col = cw + ct * 16 + lr;
        float bv = bias[col];
        #pragma unroll
        for (int t = 0; t < 2; ++t)
            #pragma unroll
            for (int reg = 0; reg < 4; ++reg){
                int rl = rw + t * 16 + lh * 4 + reg;
                Kbuf[rl * 136 + col] = __float2half(acc[t][ct][reg] + bv);
            }
    }
    __syncthreads();
    // scores: 512 dot-products (64 rows x 8 queries), 2 per thread
    #pragma unroll
    for (int p = 0; p < 2; ++p){
        int idx = tid + p * 256;
        int k = idx >> 3, i = idx & 7;
        const __half2* kr = (const __half2*)(Kbuf + k * 136);
        float a = 0.f;
        #pragma unroll 8
        for (int c2 = 0; c2 < 64; ++c2){
            float2 kf = __half22float2(kr[c2]);
            a += kf.x * Qs[i][2 * c2] + kf.y * Qs[i][2 * c2 + 1];
        }
        st[(size_t)b * 8192 + (size_t)((r0 & 1023) + k) * 8 + i] = a;
    }
}

// ---------------- Opart addressing: f32 partials packed into B0[:,64:128] ----------------
__device__ __forceinline__ float* opart_ptr(__half* B0, size_t L){
    return (float*)(B0 + (L >> 5) * 128 + 64) + (L & 31);
}

// ---------------- fused V-GEMM + partial PV ----------------
__global__ __launch_bounds__(256) void k_vpv(const __half* __restrict__ Alo,
        const __half* __restrict__ Ahi, const __half* __restrict__ Wt,
        const float* __restrict__ bias, const float* __restrict__ st,
        __half* __restrict__ B0op){
    __shared__ __half Xsm[64 * 136];
    __shared__ __half Wsm[128 * 136];
    __shared__ __half Vt[128 * 74];     // transposed V: [col][row]
    __shared__ float at[64][8];
    const int r0 = blockIdx.x * 64;
    const int b  = r0 >> 10;
    const int tid = threadIdx.x;
    mfma128_stage(Alo, Ahi, Wt, Xsm, Wsm, r0, tid);
    #pragma unroll
    for (int it = 0; it < 2; ++it){
        int idx = tid + it * 256;       // 512
        int k = idx >> 3, i = idx & 7;
        at[k][i] = st[(size_t)b * 8192 + (size_t)((r0 & 1023) + k) * 8 + i];
    }
    __syncthreads();
    floatx4 acc[2][4];
    mfma128_compute(Xsm, Wsm, tid, acc);
    const int wv = tid >> 6, lane = tid & 63, lr = lane & 15, lh = lane >> 4;
    const int rw = (wv >> 1) * 32, cw = (wv & 1) * 64;
    #pragma unroll
    for (int ct = 0; ct < 4; ++ct){
        int col = cw + ct * 16 + lr;
        float bv = bias[col];
        #pragma unroll
        for (int t = 0; t < 2; ++t)
            #pragma unroll
            for (int reg = 0; reg < 4; ++reg){
                int rl = rw + t * 16 + lh * 4 + reg;
                Vt[col * 74 + rl] = __float2half(acc[t][ct][reg] + bv);
            }
    }
    __syncthreads();
    // partial PV: O_part[i][c] = sum_{k<64} at[k][i] * V[k][c]
    int i = tid >> 5, c2 = tid & 31;
    const __half2* v0 = (const __half2*)(Vt + (2 * c2) * 74);
    const __half2* v1 = (const __half2*)(Vt + (2 * c2 + 1) * 74);
    const __half2* v2 = (const __half2*)(Vt + (2 * c2 + 64) * 74);
    const __half2* v3 = (const __half2*)(Vt + (2 * c2 + 65) * 74);
    float a0 = 0.f, a1 = 0.f, a2 = 0.f, a3 = 0.f;
    for (int k2 = 0; k2 < 32; ++k2){
        float w0 = at[2 * k2][i], w1 = at[2 * k2 + 1][i];
        float2 f0 = __half22float2(v0[k2]); a0 += w0 * f0.x + w1 * f0.y;
        float2 f1 = __half22float2(v1[k2]); a1 += w0 * f1.x + w1 * f1.y;
        float2 f2 = __half22float2(v2[k2]); a2 += w0 * f2.x + w1 * f2.y;
        float2 f3 = __half22float2(v3[k2]); a3 += w0 * f3.x + w1 * f3.y;
    }
    size_t base = ((size_t)blockIdx.x * 8 + i) * 128;
    *opart_ptr(B0op, base + 2 * c2)      = a0;
    *opart_ptr(B0op, base + 2 * c2 + 1)  = a1;
    *opart_ptr(B0op, base + 2 * c2 + 64) = a2;
    *opart_ptr(B0op, base + 2 * c2 + 65) = a3;
}

// ---------------- reduce partials: pvout[b,i,c] = sum_{j<16} Opart[b*16+j][i][c] ----
__global__ void k_oreduce(const __half* __restrict__ B0op, float* __restrict__ pvout){
    int idx = blockIdx.x * 256 + threadIdx.x;   // 262144
    int bi = idx >> 7, c = idx & 127;
    int b = bi >> 3, i = bi & 7;
    float s = 0.f;
    #pragma unroll
    for (int j = 0; j < 16; ++j){
        size_t L = (((size_t)(b * 16 + j) * 8 + i) << 7) + c;
        s += *((const float*)(B0op + (L >> 5) * 128 + 64) + (L & 31));
    }
    pvout[idx] = s;
}

// ---------------- MFMA layer1: x f32 [N,32] @ Wt1, scaled by dinv -> B0 f16 [N,128] ----
__global__ __launch_bounds__(256) void k_mfma_l1(const float* __restrict__ X,
        const __half* __restrict__ Wt, const float* __restrict__ dinv,
        __half* __restrict__ Y){
    constexpr int KD = 32, PD = 40, CO = 128;
    __shared__ __half Xs[64 * PD];
    __shared__ __half Ws[CO * PD];
    __shared__ float dvs[64];
    const int r0 = blockIdx.x * 64;
    const int tid = threadIdx.x;
    #pragma unroll
    for (int it = 0; it < 2; ++it){
        int idx = tid + it * 256;
        int row = idx >> 3, q = idx & 7;
        float4 f = ((const float4*)(X + (size_t)(r0 + row) * KD))[q];
        *(__half2*)(Xs + row * PD + q * 4)     = __floats2half2_rn(f.x, f.y);
        *(__half2*)(Xs + row * PD + q * 4 + 2) = __floats2half2_rn(f.z, f.w);
    }
    #pragma unroll
    for (int it = 0; it < 2; ++it){
        int idx = tid + it * 256;
        int row = idx >> 2, q = idx & 3;
        uint4 u = ((const uint4*)(Wt + (size_t)row * KD))[q];
        *(uint4*)(Ws + row * PD + q * 8) = u;
    }
    if (tid < 64) dvs[tid] = dinv[r0 + tid];
    __syncthreads();
    const int wv = tid >> 6, lane = tid & 63, lr = lane & 15, lh = lane >> 4;
    const int rw = (wv >> 1) * 32;
    const int cw = (wv & 1) * 64;
    floatx4 acc[2][4];
    #pragma unroll
    for (int t = 0; t < 2; ++t)
        #pragma unroll
        for (int ct = 0; ct < 4; ++ct) acc[t][ct] = (floatx4){0.f, 0.f, 0.f, 0.f};
    int kb = lh * 8;
    half8 a0 = *(const half8*)(Xs + (rw + lr) * PD + kb);
    half8 a1 = *(const half8*)(Xs + (rw + 16 + lr) * PD + kb);
    #pragma unroll
    for (int ct = 0; ct < 4; ++ct){
        half8 b = *(const half8*)(Ws + (cw + ct * 16 + lr) * PD + kb);
        acc[0][ct] = __builtin_amdgcn_mfma_f32_16x16x32_f16(a0, b, acc[0][ct], 0, 0, 0);
        acc[1][ct] = __builtin_amdgcn_mfma_f32_16x16x32_f16(a1, b, acc[1][ct], 0, 0, 0);
    }
    #pragma unroll
    for (int ct = 0; ct < 4; ++ct){
        int col = cw + ct * 16 + lr;
        #pragma unroll
        for (int t = 0; t < 2; ++t)
            #pragma unroll
            for (int reg = 0; reg < 4; ++reg){
                int rl = rw + t * 16 + lh * 4 + reg;
                Y[(size_t)(r0 + rl) * CO + col] = __float2half(acc[t][ct][reg] * dvs[rl]);
            }
    }
}

// ---------------- fused gather + bias + selu: 8 thr/node x uint4 (16B), ILP-8 ----------------
// 8 node-streams per wave x ILP-8 = 64 outstanding row-reads per wave.
#define GACC4(v) { float2 g0_ = __half22float2(*(const __half2*)&(v).x); \
                   float2 g1_ = __half22float2(*(const __half2*)&(v).y); \
                   float2 g2_ = __half22float2(*(const __half2*)&(v).z); \
                   float2 g3_ = __half22float2(*(const __half2*)&(v).w); \
                   a0 += g0_.x; a1 += g0_.y; a2 += g1_.x; a3 += g1_.y; \
                   a4 += g2_.x; a5 += g2_.y; a6 += g3_.x; a7 += g3_.y; }
__global__ __launch_bounds__(256) void k_gather64(const int* __restrict__ indptr,
        const int* __restrict__ esrc, const float* __restrict__ dinv,
        const uint4* __restrict__ Xs, int xsu, int xoff,
        const float* __restrict__ bias, int boff,
        uint4* __restrict__ Yo, int ysu){
    int t = blockIdx.x * blockDim.x + threadIdx.x;
    int node = t >> 3;
    if (node >= NNODES) return;
    int c8 = t & 7;
    float dn = dinv[node];
    int beg = indptr[node], end = indptr[node + 1];
    const uint4* xp = Xs + xoff + c8;
    uint4 u = xp[(size_t)node * xsu];
    float a0, a1, a2, a3, a4, a5, a6, a7;
    {
        float2 s0 = __half22float2(*(const __half2*)&u.x);
        float2 s1 = __half22float2(*(const __half2*)&u.y);
        float2 s2 = __half22float2(*(const __half2*)&u.z);
        float2 s3 = __half22float2(*(const __half2*)&u.w);
        a0 = s0.x; a1 = s0.y; a2 = s1.x; a3 = s1.y;
        a4 = s2.x; a5 = s2.y; a6 = s3.x; a7 = s3.y;
    }
    int j = beg;
    for (; j + 8 <= end; j += 8){
        int n0 = esrc[j],   n1 = esrc[j+1], n2 = esrc[j+2], n3 = esrc[j+3];
        int n4 = esrc[j+4], n5 = esrc[j+5], n6 = esrc[j+6], n7 = esrc[j+7];
        uint4 v0 = xp[(size_t)n0 * xsu];
        uint4 v1 = xp[(size_t)n1 * xsu];
        uint4 v2 = xp[(size_t)n2 * xsu];
        uint4 v3 = xp[(size_t)n3 * xsu];
        uint4 v4 = xp[(size_t)n4 * xsu];
        uint4 v5 = xp[(size_t)n5 * xsu];
        uint4 v6 = xp[(size_t)n6 * xsu];
        uint4 v7 = xp[(size_t)n7 * xsu];
        GACC4(v0) GACC4(v1) GACC4(v2) GACC4(v3)
        GACC4(v4) GACC4(v5) GACC4(v6) GACC4(v7)
    }
    for (; j + 4 <= end; j += 4){
        int n0 = esrc[j], n1 = esrc[j+1], n2 = esrc[j+2], n3 = esrc[j+3];
        uint4 v0 = xp[(size_t)n0 * xsu];
        uint4 v1 = xp[(size_t)n1 * xsu];
        uint4 v2 = xp[(size_t)n2 * xsu];
        uint4 v3 = xp[(size_t)n3 * xsu];
        GACC4(v0) GACC4(v1) GACC4(v2) GACC4(v3)
    }
    for (; j < end; ++j){
        uint4 v = xp[(size_t)esrc[j] * xsu];
        GACC4(v)
    }
    int ch = boff + 8 * c8;
    a0 = selu_f(a0 * dn + bias[ch + 0]);
    a1 = selu_f(a1 * dn + bias[ch + 1]);
    a2 = selu_f(a2 * dn + bias[ch + 2]);
    a3 = selu_f(a3 * dn + bias[ch + 3]);
    a4 = selu_f(a4 * dn + bias[ch + 4]);
    a5 = selu_f(a5 * dn + bias[ch + 5]);
    a6 = selu_f(a6 * dn + bias[ch + 6]);
    a7 = selu_f(a7 * dn + bias[ch + 7]);
    uint4 o;
    *(__half2*)&o.x = __floats2half2_rn(a0, a1);
    *(__half2*)&o.y = __floats2half2_rn(a2, a3);
    *(__half2*)&o.z = __floats2half2_rn(a4, a5);
    *(__half2*)&o.w = __floats2half2_rn(a6, a7);
    Yo[(size_t)node * ysu + c8] = o;
}

// ---------------- per-graph masked-node selection + shuffle ----------------
__global__ void k_qnode(const float* __restrict__ x, const int* __restrict__ shuf,
                        int* __restrict__ qnode){
    int b = blockIdx.x;
    int lane = threadIdx.x;   // 64
    __shared__ int list[MAXN];
    int localIdx[16];
    int cnt = 0;
    #pragma unroll
    for (int j = 0; j < 16; ++j){
        int node = lane * 16 + j;
        float m = x[(size_t)(b * NNPG + node) * INCH + (INCH - 3)];
        if (m > 0.5f){ if (cnt < 16) localIdx[cnt] = node; cnt++; }
    }
    int pref = cnt;
    #pragma unroll
    for (int off = 1; off < 64; off <<= 1){
        int v = __shfl_up(pref, off);
        if (lane >= off) pref += v;
    }
    pref -= cnt;
    for (int t = 0; t < cnt; ++t){
        int pos = pref + t;
        if (pos < MAXN) list[pos] = localIdx[t];
    }
    __syncthreads();
    if (lane < MAXN){
        int sidx = shuf[b * MAXN + lane];
        qnode[b * MAXN + lane] = b * NNPG + list[sidx];
    }
}

// ---------------- Q = (h2[qnode] @ Wq + bq) / sqrt(H); h2 split in B1/B0 ----------------
__global__ __launch_bounds__(128) void k_qgemm(const __half* __restrict__ hLo,
        const __half* __restrict__ hHi, const int* __restrict__ qnode,
        const float* __restrict__ Wq, const float* __restrict__ bq, float* __restrict__ Q){
    __shared__ float hs[HD];
    int row = blockIdx.x;
    int c = threadIdx.x;
    int node = qnode[row];
    if (c < 64) hs[c] = __half2float(hLo[(size_t)node * 64 + c]);
    else        hs[c] = __half2float(hHi[(size_t)node * 128 + (c - 64)]);
    __syncthreads();
    float acc = bq[c];
    for (int k = 0; k < HD; ++k) acc += hs[k] * Wq[k * HD + c];
    Q[row * HD + c] = acc * 0.08838834764831845f;
}

// ---------------- softmax over k for each (b,i); scores_t [b][k][8] in-place ----------------
__global__ __launch_bounds__(256) void k_softmax2(float* __restrict__ st){
    int b = blockIdx.x, tid = threadIdx.x;
    int wv = tid >> 6, lane = tid & 63;
    float* base = st + (size_t)b * NNPG * MAXN;
    float v[4][MAXN];
    #pragma unroll
    for (int r = 0; r < 4; ++r){
        int k = tid + r * 256;
        float4 a0 = ((const float4*)(base + k * MAXN))[0];
        float4 a1 = ((const float4*)(base + k * MAXN))[1];
        v[r][0]=a0.x; v[r][1]=a0.y; v[r][2]=a0.z; v[r][3]=a0.w;
        v[r][4]=a1.x; v[r][5]=a1.y; v[r][6]=a1.z; v[r][7]=a1.w;
    }
    float m[MAXN];
    #pragma unroll
    for (int i = 0; i < MAXN; ++i)
        m[i] = fmaxf(fmaxf(v[0][i], v[1][i]), fmaxf(v[2][i], v[3][i]));
    #pragma unroll
    for (int off = 32; off; off >>= 1)
        #pragma unroll
        for (int i = 0; i < MAXN; ++i) m[i] = fmaxf(m[i], __shfl_xor(m[i], off));
    __shared__ float red[2][4][MAXN];
    if (lane == 0)
        #pragma unroll
        for (int i = 0; i < MAXN; ++i) red[0][wv][i] = m[i];
    __syncthreads();
    #pragma unroll
    for (int i = 0; i < MAXN; ++i)
        m[i] = fmaxf(fmaxf(red[0][0][i], red[0][1][i]), fmaxf(red[0][2][i], red[0][3][i]));
    float s[MAXN];
    #pragma unroll
    for (int i = 0; i < MAXN; ++i) s[i] = 0.f;
    #pragma unroll
    for (int r = 0; r < 4; ++r)
        #pragma unroll
        for (int i = 0; i < MAXN; ++i){
            v[r][i] = expf(v[r][i] - m[i]);
            s[i] += v[r][i];
        }
    #pragma unroll
    for (int off = 32; off; off >>= 1)
        #pragma unroll
        for (int i = 0; i < MAXN; ++i) s[i] += __shfl_xor(s[i], off);
    if (lane == 0)
        #pragma unroll
        for (int i = 0; i < MAXN; ++i) red[1][wv][i] = s[i];
    __syncthreads();
    #pragma unroll
    for (int i = 0; i < MAXN; ++i){
        float tot = red[1][0][i] + red[1][1][i] + red[1][2][i] + red[1][3][i];
        s[i] = 1.0f / tot;
    }
    #pragma unroll
    for (int r = 0; r < 4; ++r){
        int k = tid + r * 256;
        float4 a0 = make_float4(v[r][0]*s[0], v[r][1]*s[1], v[r][2]*s[2], v[r][3]*s[3]);
        float4 a1 = make_float4(v[r][4]*s[4], v[r][5]*s[5], v[r][6]*s[6], v[r][7]*s[7]);
        ((float4*)(base + k * MAXN))[0] = a0;
        ((float4*)(base + k * MAXN))[1] = a1;
    }
}

// ---------------- tail: Wo+bo+selu then Wfc+bfc -> out[b][8] ----------------
__global__ __launch_bounds__(256) void k_tail(const float* __restrict__ pvout,
        const float* __restrict__ Wo, const float* __restrict__ bo,
        const float* __restrict__ Wfc, const float* __restrict__ bfc,
        float* __restrict__ out){
    int b = blockIdx.x;
    int tid = threadIdx.x;
    __shared__ float pv[MAXN * HD];
    __shared__ float sol[MAXN * HD];
    __shared__ float red[64];
    for (int idx = tid; idx < MAXN * HD / 4; idx += 256)
        ((float4*)pv)[idx] = ((const float4*)(pvout + (size_t)b * MAXN * HD))[idx];
    __syncthreads();
    int c = tid & 127;
    int grp = tid >> 7;
    float bb = bo[c];
    float acc[4];
    #pragma unroll
    for (int j = 0; j < 4; ++j) acc[j] = bb;
    for (int k = 0; k < HD; ++k){
        float w = Wo[k * HD + c];
        #pragma unroll
        for (int j = 0; j < 4; ++j) acc[j] += pv[(grp*4 + j) * HD + k] * w;
    }
    #pragma unroll
    for (int j = 0; j < 4; ++j) sol[(grp*4 + j) * HD + c] = selu_f(acc[j]);
    __syncthreads();
    if (tid < 64){
        int j = tid & 7;
        int part = tid >> 3;
        float p = 0.f;
        for (int m = part * 128; m < part * 128 + 128; ++m) p += sol[m] * Wfc[m * MAXN + j];
        red[tid] = p;
    }
    __syncthreads();
    if (tid < MAXN){
        float s = bfc[tid];
        #pragma unroll
        for (int part = 0; part < 8; ++part) s += red[part * 8 + tid];
        out[b * MAXN + tid] = s;
    }
}

extern "C" void kernel_launch(void* const* d_in, const int* in_sizes, int n_in,
                              void* d_out, int out_size, void* d_ws, size_t ws_size,
                              hipStream_t stream) {
    const float* x    = (const float*)d_in[0];
    const int*   edge = (const int*)d_in[1];
    const int*   shuf = (const int*)d_in[2];
    const float* W1   = (const float*)d_in[3];
    const float* b1   = (const float*)d_in[4];
    const float* W2   = (const float*)d_in[5];
    const float* b2   = (const float*)d_in[6];
    const float* Wq   = (const float*)d_in[7];
    const float* bq   = (const float*)d_in[8];
    const float* Wk   = (const float*)d_in[9];
    const float* bk   = (const float*)d_in[10];
    const float* Wv   = (const float*)d_in[11];
    const float* bv   = (const float*)d_in[12];
    const float* Wo   = (const float*)d_in[13];
    const float* bo   = (const float*)d_in[14];
    const float* Wfc  = (const float*)d_in[15];
    const float* bfc  = (const float*)d_in[16];
    float* out = (float*)d_out;

    // workspace layout — ~107.1 MiB
    char* w = (char*)d_ws;
    __half* B0    = (__half*)w;  w += (size_t)NNODES * HD * sizeof(__half);    // 64 MiB
    __half* B1    = (__half*)w;  w += (size_t)NNODES * 64 * sizeof(__half);    // 32 MiB (ecur+degB during CSR build)
    float*  R1    = (float*)w;   w += (size_t)NNODES * sizeof(float);          // 1 MiB: dinv (pvout after)
    int*    R2    = (int*)w;     w += (size_t)NNODES * sizeof(int);            // 1 MiB: degA (Qb after)
    int*    indptr= (int*)w;     w += ((size_t)NNODES + 64) * sizeof(int);
    int*    bsum  = (int*)w;     w += 1024;
    int*    qnode = (int*)w;     w += 8192;
    __half* Wt1   = (__half*)w;  w += 128 * INCH * sizeof(__half);
    __half* Wt2   = (__half*)w;  w += 128 * HD * sizeof(__half);
    __half* Wtk   = (__half*)w;  w += 128 * HD * sizeof(__half);
    __half* Wtv   = (__half*)w;  w += 128 * HD * sizeof(__half);
    char*   U     = w;           w += (size_t)NGRAPH * MAXN * NNPG * sizeof(float); // 8 MiB
    size_t need = (size_t)(w - (char*)d_ws);
    if (ws_size < need) return;

    float* dinv  = R1;
    float* pvout = R1;            // reused after layer-2 gathers
    int*   degA  = R2;
    float* Qb    = (float*)R2;    // reused after CSR build
    int*   ecur  = (int*)B1;      // per-edge rank (8 MiB), lives in B1 during CSR build
    int*   degB  = (int*)B1 + NEDGE;   // shadow histogram (1 MiB), also in B1
    int*   esrc  = (int*)U;       // GNN phase
    float* st    = (float*)U;     // attention phase

    const int* srcp = edge;
    const int* dstp = edge + NEDGE;

    // ---- CSR build (2-way shadow histogram; fill is atomic-free) ----
    hipMemsetAsync(degA, 0, NNODES * sizeof(int), stream);
    hipMemsetAsync(degB, 0, NNODES * sizeof(int), stream);
    k_deg<<<NEDGE / 256, 256, 0, stream>>>(dstp, degA, degB, ecur);
    k_dinv2<<<NNODES / 256, 256, 0, stream>>>(degA, degB, dinv);
    k_scan1<<<256, 256, 0, stream>>>(degB, indptr, bsum);
    k_scan2<<<1, 256, 0, stream>>>(bsum);
    k_scan3<<<256, 256, 0, stream>>>(indptr, bsum);
    k_fill<<<NEDGE / 256, 256, 0, stream>>>(srcp, dstp, indptr, ecur, degA, esrc);

    // ---- weight prep ----
    k_wprep<<<(128 * INCH) / 256, 256, 0, stream>>>(W1, Wt1, INCH);
    k_wprep<<<(128 * HD) / 256, 256, 0, stream>>>(W2, Wt2, HD);
    k_wprep<<<(128 * HD) / 256, 256, 0, stream>>>(Wk, Wtk, HD);
    k_wprep<<<(128 * HD) / 256, 256, 0, stream>>>(Wv, Wtv, HD);

    const int gBlocks = (NNODES * 8) / 256;   // gather grid (8 thr/node)

    // ---- layer 1: scaled xw1 full in B0; gather h0->B1, h1->B0[:,0:64] ----
    k_mfma_l1<<<NNODES / 64, 256, 0, stream>>>(x, Wt1, dinv, B0);
    k_gather64<<<gBlocks, 256, 0, stream>>>(indptr, esrc, dinv,
            (const uint4*)B0, 16, 0, b1, 0,  (uint4*)B1, 8);
    k_gather64<<<gBlocks, 256, 0, stream>>>(indptr, esrc, dinv,
            (const uint4*)B0, 16, 8, b1, 64, (uint4*)B0, 16);
    // ---- layer 2: split-A GEMM -> scaled xw2 full in B0 (in-place); gathers ----
    k_mfma_sp<<<NNODES / 64, 256, 0, stream>>>(B1, B0, Wt2, dinv, B0);
    k_gather64<<<gBlocks, 256, 0, stream>>>(indptr, esrc, dinv,
            (const uint4*)B0, 16, 0, b2, 0,  (uint4*)B1, 8);
    k_gather64<<<gBlocks, 256, 0, stream>>>(indptr, esrc, dinv,
            (const uint4*)B0, 16, 8, b2, 64, (uint4*)B0, 16);
    // h2: cols 0-63 in B1 (stride 64), cols 64-127 in B0[:,0:64] (stride 128)

    // ---- attention ----
    k_qnode<<<NGRAPH, 64, 0, stream>>>(x, shuf, qnode);
    k_qgemm<<<NGRAPH * MAXN, 128, 0, stream>>>(B1, B0, qnode, Wq, bq, Qb);

    // fused K-GEMM + scores (K lives only in LDS)
    k_kscores<<<NNODES / 64, 256, 0, stream>>>(B1, B0, Wtk, bk, Qb, st);
    k_softmax2<<<NGRAPH, 256, 0, stream>>>(st);
    // fused V-GEMM + partial PV -> Opart in dead B0[:,64:128] region
    k_vpv<<<NNODES / 64, 256, 0, stream>>>(B1, B0, Wtv, bv, st, B0);
    k_oreduce<<<(NGRAPH * MAXN * HD) / 256, 256, 0, stream>>>(B0, pvout);

    k_tail<<<NGRAPH, 256, 0, stream>>>(pvout, Wo, bo, Wfc, bfc, out);
}